// Round 6
// baseline (357.625 us; speedup 1.0000x reference)
//
#include <hip/hip_runtime.h>
#include <math.h>

#define T_TOK 2048
#define HD 768
#define ID 1536
#define NE 8
#define CAP 768
#define TK 4096
#define RT 12      // max 128-row tiles per expert (2*CAP/128)
#define NB1 24     // ID/64 col-strips for gemm1
#define KC1 24     // HD/32 K-steps for gemm1
#define NB2 12     // HD/64 col-strips for gemm2
#define KC2 48     // ID/32 K-steps for gemm2
#define DONE 0x13572468

typedef __bf16 bf16_t;
typedef __bf16 bf16x8 __attribute__((ext_vector_type(8)));
typedef __bf16 bf16x4 __attribute__((ext_vector_type(4)));
typedef float floatx4 __attribute__((ext_vector_type(4)));

__device__ __forceinline__ void gld16(const bf16_t* g, bf16_t* l) {
  __builtin_amdgcn_global_load_lds(
      (__attribute__((address_space(1))) void*)(g),
      (__attribute__((address_space(3))) void*)(l),
      16, 0, 0);
}

// ---------------- K1: routing + out-zero + weight repack + fused scan ----------
// blocks [0,512): routing (4 tokens/block, wave per token) + zero out slice;
//                 each wave releases flags[token] after a device fence.
// blocks [512,2240): float4 repack fp32 -> pre-swizzled bf16 blobs (no LDS).
// block 2240: spins on the 2048 flags, then runs capacity scan + placement + aux.
__global__ void k_prep(const float* __restrict__ x, const float* __restrict__ wg,
                       const float* __restrict__ w1, const float* __restrict__ w3,
                       const float* __restrict__ w2,
                       bf16_t* __restrict__ xbf, bf16_t* __restrict__ w1b,
                       bf16_t* __restrict__ w3b, bf16_t* __restrict__ w2b,
                       int2* __restrict__ idx2, float2* __restrict__ wc2,
                       float* __restrict__ probs8, float* __restrict__ outz,
                       int* __restrict__ tok_of_row, float* __restrict__ wgt_of_row,
                       int2* __restrict__ cnt_start, float* __restrict__ aux_out,
                       int* __restrict__ flags) {
  __shared__ int2 sIdx[2048];          // used only by the scan block (16.5 KB)
  __shared__ int sTot[16];
  __shared__ int sPos[8];
  __shared__ float sImp[4][8];
  int b = blockIdx.x;
  int tid = threadIdx.x;
  if (b < 512) {
    // ---- routing ----
#pragma unroll
    for (int k2 = 0; k2 < 3; ++k2) {
      float4 z = make_float4(0.f, 0.f, 0.f, 0.f);
      *(float4*)(outz + (size_t)b * 3072 + k2 * 1024 + tid * 4) = z;
    }
    int t = b * 4 + (tid >> 6);
    int lane = tid & 63;
    const float* xr = x + (size_t)t * HD;
    int off = lane * 12;
    float4 a = *(const float4*)(xr + off);
    float4 bv = *(const float4*)(xr + off + 4);
    float4 c = *(const float4*)(xr + off + 8);
    float xv[12] = {a.x, a.y, a.z, a.w, bv.x, bv.y, bv.z, bv.w, c.x, c.y, c.z, c.w};
    bf16x4 s0, s1, s2;
#pragma unroll
    for (int j = 0; j < 4; ++j) { s0[j] = (bf16_t)xv[j]; s1[j] = (bf16_t)xv[4 + j]; s2[j] = (bf16_t)xv[8 + j]; }
    bf16_t* xo = xbf + (size_t)t * HD + off;
    *(bf16x4*)xo = s0; *(bf16x4*)(xo + 4) = s1; *(bf16x4*)(xo + 8) = s2;

    float acc[8] = {0, 0, 0, 0, 0, 0, 0, 0};
#pragma unroll
    for (int jj = 0; jj < 12; ++jj) {
      const float4* wr = (const float4*)(wg + (size_t)(off + jj) * 8);
      float4 w0 = wr[0], w1v = wr[1];
      float v = xv[jj];
      acc[0] += v * w0.x; acc[1] += v * w0.y; acc[2] += v * w0.z; acc[3] += v * w0.w;
      acc[4] += v * w1v.x; acc[5] += v * w1v.y; acc[6] += v * w1v.z; acc[7] += v * w1v.w;
    }
#pragma unroll
    for (int e = 0; e < 8; ++e) {
      float v = acc[e];
      for (int s = 1; s < 64; s <<= 1) v += __shfl_xor(v, s, 64);
      acc[e] = v;
    }
    float mx = acc[0];
#pragma unroll
    for (int e = 1; e < 8; ++e) mx = fmaxf(mx, acc[e]);
    float p[8], sum = 0.f;
#pragma unroll
    for (int e = 0; e < 8; ++e) { p[e] = __expf(acc[e] - mx); sum += p[e]; }
#pragma unroll
    for (int e = 0; e < 8; ++e) p[e] /= sum;
    if (lane == 0) {
      float4 P0 = make_float4(p[0], p[1], p[2], p[3]);
      float4 P1 = make_float4(p[4], p[5], p[6], p[7]);
      *(float4*)&probs8[t * 8] = P0;
      *(float4*)&probs8[t * 8 + 4] = P1;
      int e0 = 0;
#pragma unroll
      for (int e = 1; e < 8; ++e) if (p[e] > p[e0]) e0 = e;
      int e1 = (e0 == 0) ? 1 : 0;
#pragma unroll
      for (int e = 0; e < 8; ++e) if (e != e0 && p[e] > p[e1]) e1 = e;
      float denom = p[e0] + p[e1] + 1e-8f;
      float w0c = fminf(fmaxf(p[e0] / denom, 1e-8f), 10.f);
      float w1c = fminf(fmaxf(p[e1] / denom, 1e-8f), 10.f);
      idx2[t] = make_int2(e0, e1);
      wc2[t] = make_float2(w0c, w1c);
      __threadfence();                 // publish this wave's routing outputs
      atomicExch(&flags[t], DONE);     // release
    }
  } else if (b < 2240) {
    // ---- float4 repack: one kc-tile (64n x 32k -> 2048 bf16) per wave-iter ----
    int rb = b - 512;  // [0,1728): 576 w1 + 576 w3 + 576 w2; 8 kc-tiles/block
    const float* src; bf16_t* dst; int C; int kc0;
    if (rb < 1152) {
      int m = rb >= 576;
      int r3 = m ? rb - 576 : rb;
      int pan = r3 / 3;
      kc0 = (r3 - pan * 3) * 8;
      int e = pan & 7, nb = pan >> 3;
      src = (m ? w3 : w1) + (size_t)e * HD * ID + nb * 64;
      dst = (m ? w3b : w1b) + (size_t)(e * NB1 + nb) * (KC1 * 2048);
      C = ID;
    } else {
      int q = rb - 1152;
      int pan = q / 6;
      kc0 = (q - pan * 6) * 8;
      int e = pan & 7, nb = pan >> 3;
      src = w2 + (size_t)e * ID * HD + nb * 64;
      dst = w2b + (size_t)(e * NB2 + nb) * (KC2 * 2048);
      C = HD;
    }
    int wv = tid >> 6, lane = tid & 63;
    int g = lane >> 4, m = lane & 15;
#pragma unroll
    for (int ti = 0; ti < 2; ++ti) {
      int kc = kc0 + wv + ti * 4;
      const float* sp = src + (size_t)(kc * 32 + g * 8) * C + 4 * m;
      float4 v[8];
#pragma unroll
      for (int j = 0; j < 8; ++j) v[j] = *(const float4*)(sp + (size_t)j * C);
      bf16_t* dp = dst + (size_t)kc * 2048;
#pragma unroll
      for (int c = 0; c < 4; ++c) {
        int n = 4 * m + c;
        int p = g ^ ((n >> 1) & 3);
        bf16x8 o;
#pragma unroll
        for (int j = 0; j < 8; ++j)
          o[j] = (bf16_t)((c == 0) ? v[j].x : (c == 1) ? v[j].y : (c == 2) ? v[j].z : v[j].w);
        *(bf16x8*)(dp + n * 32 + p * 8) = o;
      }
    }
  } else {
    // ---- fused scan block: wait for all routing waves, then scan ----
    for (int i = tid; i < 2048; i += 256)
      while (atomicAdd(&flags[i], 0) != DONE) { }
    __threadfence();                   // acquire
    __syncthreads();
    for (int i = tid; i < 2048; i += 256) sIdx[i] = idx2[i];
    // importance partial: 8 tokens per thread
    float im[8] = {0, 0, 0, 0, 0, 0, 0, 0};
    const float4* pp = (const float4*)probs8;
#pragma unroll
    for (int tt = 0; tt < 8; ++tt) {
      float4 u0 = pp[(tid * 8 + tt) * 2], u1 = pp[(tid * 8 + tt) * 2 + 1];
      im[0] += u0.x; im[1] += u0.y; im[2] += u0.z; im[3] += u0.w;
      im[4] += u1.x; im[5] += u1.y; im[6] += u1.z; im[7] += u1.w;
    }
    int w = tid >> 6, lane = tid & 63;
#pragma unroll
    for (int e = 0; e < 8; ++e) {
      float v = im[e];
      for (int d = 1; d < 64; d <<= 1) v += __shfl_xor(v, d, 64);
      im[e] = v;
    }
    if (lane == 0) {
#pragma unroll
      for (int e = 0; e < 8; ++e) sImp[w][e] = im[e];
    }
    __syncthreads();
    // count + scan: 4 (slot,expert) columns per wave
    int t0 = lane * 32;
    int excl[4];
#pragma unroll
    for (int i = 0; i < 4; ++i) {
      int col = w * 4 + i;
      int s = col >> 3, e = col & 7;
      int cnt = 0;
      for (int j = 0; j < 32; ++j) {
        int2 p = sIdx[t0 + j];
        cnt += ((s ? p.y : p.x) == e) ? 1 : 0;
      }
      int incl = cnt;
      for (int d = 1; d < 64; d <<= 1) {
        int v = __shfl_up(incl, d, 64);
        if (lane >= d) incl += v;
      }
      excl[i] = incl - cnt;
      if (lane == 63) sTot[col] = incl;
    }
    __syncthreads();
    if (tid == 0) {
      int run = 0; float a = 0.f;
      for (int ee = 0; ee < 8; ++ee) {
        float impv = sImp[0][ee] + sImp[1][ee] + sImp[2][ee] + sImp[3][ee];
        int k = min(sTot[ee], CAP) + min(sTot[8 + ee], CAP);
        sPos[ee] = run;
        cnt_start[ee] = make_int2(run, k);
        a += ((float)k / (float)TK) * (impv / (float)T_TOK);
        run += k;
      }
      a *= (float)NE;
      int dropped = TK - run;
      if (dropped > 0) a += (float)dropped / (float)T_TOK * 0.1f;
      aux_out[0] = fminf(a, 1.f) * 0.001f;
    }
    __syncthreads();
#pragma unroll
    for (int i = 0; i < 4; ++i) {
      int col = w * 4 + i;
      int s = col >> 3, e = col & 7;
      int rank = excl[i];
      for (int j = 0; j < 32; ++j) {
        int t = t0 + j;
        int2 p = sIdx[t];
        if ((s ? p.y : p.x) == e) {
          rank++;
          if (rank <= CAP) {
            int pos = atomicAdd(&sPos[e], 1);
            tok_of_row[pos] = t;
            float2 wv2 = wc2[t];
            wgt_of_row[pos] = s ? wv2.y : wv2.x;
          }
        }
      }
    }
  }
}

// ---------------- K3: grouped GEMM1 (g,u) + SiLU -> h ----------------
// grid 2304: bx = e + 8*(nb*RT + rt); tile 128m x 64n
__global__ __launch_bounds__(256, 4)
void k_gemm1(const bf16_t* __restrict__ xbf, const bf16_t* __restrict__ w1b,
             const bf16_t* __restrict__ w3b, const int* __restrict__ tok_of_row,
             const int2* __restrict__ cnt_start, bf16_t* __restrict__ h_ws) {
  int e = blockIdx.x & 7;
  int t = blockIdx.x >> 3;
  int nb = t / RT, rt = t - nb * RT;
  int2 cs = cnt_start[e];
  int nrows = cs.y - rt * 128;
  if (nrows <= 0) return;
  if (nrows > 128) nrows = 128;
  int grow0 = cs.x + rt * 128;

  __shared__ __attribute__((aligned(16))) bf16_t Abuf[128 * 32];
  __shared__ __attribute__((aligned(16))) bf16_t B1buf[64 * 32];
  __shared__ __attribute__((aligned(16))) bf16_t B3buf[64 * 32];

  int tid = threadIdx.x;
  int lane = tid & 63, wv = tid >> 6;
  int wm = wv & 1, wn = wv >> 1;
  int lr = lane & 15, q = lane >> 4;
  int rdc = (q ^ ((lane >> 1) & 3)) * 8;
  int srow = lane >> 2;
  int gch = ((lane & 3) ^ ((lane >> 3) & 3)) * 8;

  int ra = wv * 32 + srow;
  int tokA0 = tok_of_row[grow0 + min(ra, nrows - 1)];
  int tokA1 = tok_of_row[grow0 + min(ra + 16, nrows - 1)];
  const bf16_t* gA0 = xbf + (size_t)tokA0 * HD + gch;
  const bf16_t* gA1 = xbf + (size_t)tokA1 * HD + gch;
  const bf16_t* p1 = w1b + (size_t)((e * NB1 + nb) * KC1) * 2048 + tid * 8;
  const bf16_t* p3 = w3b + (size_t)((e * NB1 + nb) * KC1) * 2048 + tid * 8;
  bf16_t* lA0 = &Abuf[(wv * 32) * 32];
  bf16_t* lA1 = &Abuf[(wv * 32 + 16) * 32];
  bf16_t* lB1 = &B1buf[wv * 512];
  bf16_t* lB3 = &B3buf[wv * 512];

  floatx4 accg[4][2] = {};
  floatx4 accu[4][2] = {};

  for (int kk = 0; kk < KC1; ++kk) {
    __syncthreads();
    gld16(gA0, lA0); gld16(gA1, lA1);
    gld16(p1, lB1); gld16(p3, lB3);
    gA0 += 32; gA1 += 32; p1 += 2048; p3 += 2048;
    __syncthreads();
    bf16x8 af[4], b1f[2], b3f[2];
#pragma unroll
    for (int i = 0; i < 4; ++i) af[i] = *(const bf16x8*)&Abuf[(wm * 64 + i * 16 + lr) * 32 + rdc];
#pragma unroll
    for (int i = 0; i < 2; ++i) b1f[i] = *(const bf16x8*)&B1buf[(wn * 32 + i * 16 + lr) * 32 + rdc];
#pragma unroll
    for (int i = 0; i < 2; ++i) b3f[i] = *(const bf16x8*)&B3buf[(wn * 32 + i * 16 + lr) * 32 + rdc];
#pragma unroll
    for (int i = 0; i < 4; ++i)
#pragma unroll
      for (int jj = 0; jj < 2; ++jj) {
        accg[i][jj] = __builtin_amdgcn_mfma_f32_16x16x32_bf16(af[i], b1f[jj], accg[i][jj], 0, 0, 0);
        accu[i][jj] = __builtin_amdgcn_mfma_f32_16x16x32_bf16(af[i], b3f[jj], accu[i][jj], 0, 0, 0);
      }
  }
#pragma unroll
  for (int i = 0; i < 4; ++i)
#pragma unroll
    for (int r = 0; r < 4; ++r) {
      int rl = wm * 64 + i * 16 + q * 4 + r;
      if (rl < nrows) {
        size_t rb = (size_t)(grow0 + rl) * ID + nb * 64 + wn * 32 + lr;
#pragma unroll
        for (int jj = 0; jj < 2; ++jj) {
          float gg = accg[i][jj][r], uu = accu[i][jj][r];
          float sg = gg / (1.f + __expf(-gg));
          h_ws[rb + jj * 16] = (bf16_t)(sg * uu);
        }
      }
    }
}

// ---------------- K4: grouped GEMM2 + fused combine (atomicAdd) ----------------
// grid 1152: bx = e + 8*(nb*RT + rt); tile 128m x 64n
__global__ __launch_bounds__(256, 4)
void k_gemm2(const bf16_t* __restrict__ h_ws, const bf16_t* __restrict__ w2b,
             const int* __restrict__ tok_of_row, const float* __restrict__ wgt_of_row,
             const int2* __restrict__ cnt_start, float* __restrict__ out) {
  int e = blockIdx.x & 7;
  int t = blockIdx.x >> 3;
  int nb = t / RT, rt = t - nb * RT;
  int2 cs = cnt_start[e];
  int nrows = cs.y - rt * 128;
  if (nrows <= 0) return;
  if (nrows > 128) nrows = 128;
  int grow0 = cs.x + rt * 128;

  __shared__ __attribute__((aligned(16))) bf16_t Abuf[128 * 32];
  __shared__ __attribute__((aligned(16))) bf16_t Bbuf[64 * 32];

  int tid = threadIdx.x;
  int lane = tid & 63, wv = tid >> 6;
  int wm = wv & 1, wn = wv >> 1;
  int lr = lane & 15, q = lane >> 4;
  int rdc = (q ^ ((lane >> 1) & 3)) * 8;
  int srow = lane >> 2;
  int gch = ((lane & 3) ^ ((lane >> 3) & 3)) * 8;

  int ra = wv * 32 + srow;
  const bf16_t* gA0 = h_ws + (size_t)(grow0 + min(ra, nrows - 1)) * ID + gch;
  const bf16_t* gA1 = h_ws + (size_t)(grow0 + min(ra + 16, nrows - 1)) * ID + gch;
  const bf16_t* pB = w2b + (size_t)((e * NB2 + nb) * KC2) * 2048 + tid * 8;
  bf16_t* lA0 = &Abuf[(wv * 32) * 32];
  bf16_t* lA1 = &Abuf[(wv * 32 + 16) * 32];
  bf16_t* lB = &Bbuf[wv * 512];

  floatx4 acc[4][2] = {};

  for (int kk = 0; kk < KC2; ++kk) {
    __syncthreads();
    gld16(gA0, lA0); gld16(gA1, lA1);
    gld16(pB, lB);
    gA0 += 32; gA1 += 32; pB += 2048;
    __syncthreads();
    bf16x8 af[4], bfr[2];
#pragma unroll
    for (int i = 0; i < 4; ++i) af[i] = *(const bf16x8*)&Abuf[(wm * 64 + i * 16 + lr) * 32 + rdc];
#pragma unroll
    for (int i = 0; i < 2; ++i) bfr[i] = *(const bf16x8*)&Bbuf[(wn * 32 + i * 16 + lr) * 32 + rdc];
#pragma unroll
    for (int i = 0; i < 4; ++i)
#pragma unroll
      for (int jj = 0; jj < 2; ++jj)
        acc[i][jj] = __builtin_amdgcn_mfma_f32_16x16x32_bf16(af[i], bfr[jj], acc[i][jj], 0, 0, 0);
  }
#pragma unroll
  for (int i = 0; i < 4; ++i)
#pragma unroll
    for (int r = 0; r < 4; ++r) {
      int rl = wm * 64 + i * 16 + q * 4 + r;
      if (rl < nrows) {
        int grow = grow0 + rl;
        int tok = tok_of_row[grow];
        float wgt = wgt_of_row[grow];
        size_t ob = (size_t)tok * HD + nb * 64 + wn * 32 + lr;
#pragma unroll
        for (int jj = 0; jj < 2; ++jj)
          atomicAdd(&out[ob + jj * 16], wgt * acc[i][jj][r]);
      }
    }
}

extern "C" void kernel_launch(void* const* d_in, const int* in_sizes, int n_in,
                              void* d_out, int out_size, void* d_ws, size_t ws_size,
                              hipStream_t stream) {
  const float* x  = (const float*)d_in[0];
  const float* wg = (const float*)d_in[1];
  const float* w1 = (const float*)d_in[2];
  const float* w3 = (const float*)d_in[3];
  const float* w2 = (const float*)d_in[4];
  float* out = (float*)d_out;

  char* ws = (char*)d_ws;
  bf16_t* xbf  = (bf16_t*)(ws + 0);          //  3,145,728
  bf16_t* w1b  = (bf16_t*)(ws + 3145728);    // 18,874,368
  bf16_t* w3b  = (bf16_t*)(ws + 22020096);   // 18,874,368
  bf16_t* w2b  = (bf16_t*)(ws + 40894464);   // 18,874,368
  bf16_t* h_ws = (bf16_t*)(ws + 59768832);   // 12,582,912
  float*  probs8     = (float*)(ws + 72351744);   // 65,536
  int2*   idx2       = (int2*)(ws + 72417280);
  float2* wc2        = (float2*)(ws + 72433664);
  int*    tok_of_row = (int*)(ws + 72450048);
  float*  wgt_of_row = (float*)(ws + 72466432);
  int2*   cnt_start  = (int2*)(ws + 72482816);
  int*    flags      = (int*)(ws + 72482880);     // 8,192 (2048 wave flags)

  float* aux_out = out + (size_t)T_TOK * HD;

  k_prep<<<2241, 256, 0, stream>>>(x, wg, w1, w3, w2, xbf, w1b, w3b, w2b,
                                   idx2, wc2, probs8, out,
                                   tok_of_row, wgt_of_row, cnt_start, aux_out,
                                   flags);
  k_gemm1<<<8 * NB1 * RT, 256, 0, stream>>>(xbf, w1b, w3b, tok_of_row,
                                            cnt_start, h_ws);
  k_gemm2<<<8 * NB2 * RT, 256, 0, stream>>>(h_ws, w2b, tok_of_row, wgt_of_row,
                                            cnt_start, out);
}

// Round 7
// 265.054 us; speedup vs baseline: 1.3493x; 1.3493x over previous
//
#include <hip/hip_runtime.h>
#include <math.h>

#define T_TOK 2048
#define HD 768
#define ID 1536
#define NE 8
#define CAP 768
#define TK 4096
#define RT 12      // max 128-row tiles per expert (2*CAP/128)
#define NB1 24     // ID/64 col-strips for gemm1
#define KC1 24     // HD/32 K-steps for gemm1
#define NB2 12     // HD/64 col-strips for gemm2
#define KC2 48     // ID/32 K-steps for gemm2

typedef __bf16 bf16_t;
typedef __bf16 bf16x8 __attribute__((ext_vector_type(8)));
typedef __bf16 bf16x4 __attribute__((ext_vector_type(4)));
typedef float floatx4 __attribute__((ext_vector_type(4)));

__device__ __forceinline__ void gld16(const bf16_t* g, bf16_t* l) {
  __builtin_amdgcn_global_load_lds(
      (__attribute__((address_space(1))) void*)(g),
      (__attribute__((address_space(3))) void*)(l),
      16, 0, 0);
}

// ---------------- K1: routing + out-zero + float4 weight repack ----------------
// blocks [0,512): routing (4 tokens/block, wave per token) + zero out slice
// blocks [512,2240): float4 repack fp32 -> pre-swizzled bf16 blobs. Lane =
//   (octet-group g = lane>>4, col-group m = lane&15); 8x float4 loads cover
//   full 256B rows (4 fully-used segments/instr); swizzle absorbed in store.
//   NO LDS anywhere in this kernel (k6 regression: scoped LDS cost occupancy).
__global__ void k_prep(const float* __restrict__ x, const float* __restrict__ wg,
                       const float* __restrict__ w1, const float* __restrict__ w3,
                       const float* __restrict__ w2,
                       bf16_t* __restrict__ xbf, bf16_t* __restrict__ w1b,
                       bf16_t* __restrict__ w3b, bf16_t* __restrict__ w2b,
                       int2* __restrict__ idx2, float2* __restrict__ wc2,
                       float* __restrict__ probs8, float* __restrict__ outz) {
  int b = blockIdx.x;
  int tid = threadIdx.x;
  if (b < 512) {
#pragma unroll
    for (int k2 = 0; k2 < 3; ++k2) {
      float4 z = make_float4(0.f, 0.f, 0.f, 0.f);
      *(float4*)(outz + (size_t)b * 3072 + k2 * 1024 + tid * 4) = z;
    }
    int t = b * 4 + (tid >> 6);
    int lane = tid & 63;
    const float* xr = x + (size_t)t * HD;
    int off = lane * 12;
    float4 a = *(const float4*)(xr + off);
    float4 bv = *(const float4*)(xr + off + 4);
    float4 c = *(const float4*)(xr + off + 8);
    float xv[12] = {a.x, a.y, a.z, a.w, bv.x, bv.y, bv.z, bv.w, c.x, c.y, c.z, c.w};
    bf16x4 s0, s1, s2;
#pragma unroll
    for (int j = 0; j < 4; ++j) { s0[j] = (bf16_t)xv[j]; s1[j] = (bf16_t)xv[4 + j]; s2[j] = (bf16_t)xv[8 + j]; }
    bf16_t* xo = xbf + (size_t)t * HD + off;
    *(bf16x4*)xo = s0; *(bf16x4*)(xo + 4) = s1; *(bf16x4*)(xo + 8) = s2;

    float acc[8] = {0, 0, 0, 0, 0, 0, 0, 0};
#pragma unroll
    for (int jj = 0; jj < 12; ++jj) {
      const float4* wr = (const float4*)(wg + (size_t)(off + jj) * 8);
      float4 w0 = wr[0], w1v = wr[1];
      float v = xv[jj];
      acc[0] += v * w0.x; acc[1] += v * w0.y; acc[2] += v * w0.z; acc[3] += v * w0.w;
      acc[4] += v * w1v.x; acc[5] += v * w1v.y; acc[6] += v * w1v.z; acc[7] += v * w1v.w;
    }
#pragma unroll
    for (int e = 0; e < 8; ++e) {
      float v = acc[e];
      for (int s = 1; s < 64; s <<= 1) v += __shfl_xor(v, s, 64);
      acc[e] = v;
    }
    float mx = acc[0];
#pragma unroll
    for (int e = 1; e < 8; ++e) mx = fmaxf(mx, acc[e]);
    float p[8], sum = 0.f;
#pragma unroll
    for (int e = 0; e < 8; ++e) { p[e] = __expf(acc[e] - mx); sum += p[e]; }
#pragma unroll
    for (int e = 0; e < 8; ++e) p[e] /= sum;
    if (lane == 0) {
      float4 P0 = make_float4(p[0], p[1], p[2], p[3]);
      float4 P1 = make_float4(p[4], p[5], p[6], p[7]);
      *(float4*)&probs8[t * 8] = P0;
      *(float4*)&probs8[t * 8 + 4] = P1;
      int e0 = 0;
#pragma unroll
      for (int e = 1; e < 8; ++e) if (p[e] > p[e0]) e0 = e;
      int e1 = (e0 == 0) ? 1 : 0;
#pragma unroll
      for (int e = 0; e < 8; ++e) if (e != e0 && p[e] > p[e1]) e1 = e;
      float denom = p[e0] + p[e1] + 1e-8f;
      float w0c = fminf(fmaxf(p[e0] / denom, 1e-8f), 10.f);
      float w1c = fminf(fmaxf(p[e1] / denom, 1e-8f), 10.f);
      idx2[t] = make_int2(e0, e1);
      wc2[t] = make_float2(w0c, w1c);
    }
  } else {
    int rb = b - 512;  // [0,1728): 576 w1 + 576 w3 + 576 w2; 8 kc-tiles/block
    const float* src; bf16_t* dst; int C; int kc0;
    if (rb < 1152) {
      int m = rb >= 576;
      int r3 = m ? rb - 576 : rb;
      int pan = r3 / 3;
      kc0 = (r3 - pan * 3) * 8;
      int e = pan & 7, nb = pan >> 3;
      src = (m ? w3 : w1) + (size_t)e * HD * ID + nb * 64;
      dst = (m ? w3b : w1b) + (size_t)(e * NB1 + nb) * (KC1 * 2048);
      C = ID;
    } else {
      int q = rb - 1152;
      int pan = q / 6;
      kc0 = (q - pan * 6) * 8;
      int e = pan & 7, nb = pan >> 3;
      src = w2 + (size_t)e * ID * HD + nb * 64;
      dst = w2b + (size_t)(e * NB2 + nb) * (KC2 * 2048);
      C = HD;
    }
    int wv = tid >> 6, lane = tid & 63;
    int g = lane >> 4, m = lane & 15;
#pragma unroll
    for (int ti = 0; ti < 2; ++ti) {
      int kc = kc0 + wv + ti * 4;
      const float* sp = src + (size_t)(kc * 32 + g * 8) * C + 4 * m;
      float4 v[8];
#pragma unroll
      for (int j = 0; j < 8; ++j) v[j] = *(const float4*)(sp + (size_t)j * C);
      bf16_t* dp = dst + (size_t)kc * 2048;
#pragma unroll
      for (int c = 0; c < 4; ++c) {
        int n = 4 * m + c;
        int p = g ^ ((n >> 1) & 3);
        bf16x8 o;
#pragma unroll
        for (int j = 0; j < 8; ++j)
          o[j] = (bf16_t)((c == 0) ? v[j].x : (c == 1) ? v[j].y : (c == 2) ? v[j].z : v[j].w);
        *(bf16x8*)(dp + n * 32 + p * 8) = o;
      }
    }
  }
}

// ---------------- K2: capacity ranks + placement + aux (1 block) ----------------
__global__ void k_scan(const int2* __restrict__ idx2, const float2* __restrict__ wc2,
                       const float* __restrict__ probs8,
                       int* __restrict__ tok_of_row, float* __restrict__ wgt_of_row,
                       int2* __restrict__ cnt_start, float* __restrict__ aux_out) {
  __shared__ int2 sIdx[2048];
  __shared__ float2 sWc[2048];
  __shared__ int sTot[16];
  __shared__ int sPos[8];
  __shared__ float sImp[16][8];
  int tid = threadIdx.x;
  sIdx[tid] = idx2[tid]; sIdx[tid + 1024] = idx2[tid + 1024];
  sWc[tid] = wc2[tid];  sWc[tid + 1024] = wc2[tid + 1024];
  const float4* pp = (const float4*)probs8;
  float4 u0 = pp[tid * 4], u1 = pp[tid * 4 + 1], u2 = pp[tid * 4 + 2], u3 = pp[tid * 4 + 3];
  float im[8] = {u0.x + u2.x, u0.y + u2.y, u0.z + u2.z, u0.w + u2.w,
                 u1.x + u3.x, u1.y + u3.y, u1.z + u3.z, u1.w + u3.w};
#pragma unroll
  for (int e = 0; e < 8; ++e) {
    float v = im[e];
    for (int d = 1; d < 64; d <<= 1) v += __shfl_xor(v, d, 64);
    im[e] = v;
  }
  int w = tid >> 6, lane = tid & 63;
  if (lane == 0) {
#pragma unroll
    for (int e = 0; e < 8; ++e) sImp[w][e] = im[e];
  }
  __syncthreads();
  int s = w >> 3, e = w & 7;
  int t0 = lane * 32;
  int cnt = 0;
  for (int j = 0; j < 32; ++j) {
    int2 p = sIdx[t0 + j];
    cnt += ((s ? p.y : p.x) == e) ? 1 : 0;
  }
  int incl = cnt;
  for (int d = 1; d < 64; d <<= 1) {
    int v = __shfl_up(incl, d, 64);
    if (lane >= d) incl += v;
  }
  int excl = incl - cnt;
  if (lane == 63) sTot[w] = incl;
  __syncthreads();
  if (tid == 0) {
    int run = 0; float a = 0.f;
    for (int ee = 0; ee < 8; ++ee) {
      float impv = 0.f;
      for (int ww = 0; ww < 16; ++ww) impv += sImp[ww][ee];
      int k = min(sTot[ee], CAP) + min(sTot[8 + ee], CAP);
      sPos[ee] = run;
      cnt_start[ee] = make_int2(run, k);
      a += ((float)k / (float)TK) * (impv / (float)T_TOK);
      run += k;
    }
    a *= (float)NE;
    int dropped = TK - run;
    if (dropped > 0) a += (float)dropped / (float)T_TOK * 0.1f;
    aux_out[0] = fminf(a, 1.f) * 0.001f;
  }
  __syncthreads();
  int rank = excl;
  for (int j = 0; j < 32; ++j) {
    int t = t0 + j;
    int2 p = sIdx[t];
    int ex = s ? p.y : p.x;
    if (ex == e) {
      rank++;
      if (rank <= CAP) {
        int pos = atomicAdd(&sPos[e], 1);
        tok_of_row[pos] = t;
        float2 wv = sWc[t];
        wgt_of_row[pos] = s ? wv.y : wv.x;
      }
    }
  }
}

// ---------------- K3: grouped GEMM1 (g,u) + SiLU -> h ----------------
// grid 2304: bx = e + 8*(nb*RT + rt); tile 128m x 64n
__global__ __launch_bounds__(256, 4)
void k_gemm1(const bf16_t* __restrict__ xbf, const bf16_t* __restrict__ w1b,
             const bf16_t* __restrict__ w3b, const int* __restrict__ tok_of_row,
             const int2* __restrict__ cnt_start, bf16_t* __restrict__ h_ws) {
  int e = blockIdx.x & 7;
  int t = blockIdx.x >> 3;
  int nb = t / RT, rt = t - nb * RT;
  int2 cs = cnt_start[e];
  int nrows = cs.y - rt * 128;
  if (nrows <= 0) return;
  if (nrows > 128) nrows = 128;
  int grow0 = cs.x + rt * 128;

  __shared__ __attribute__((aligned(16))) bf16_t Abuf[128 * 32];
  __shared__ __attribute__((aligned(16))) bf16_t B1buf[64 * 32];
  __shared__ __attribute__((aligned(16))) bf16_t B3buf[64 * 32];

  int tid = threadIdx.x;
  int lane = tid & 63, wv = tid >> 6;
  int wm = wv & 1, wn = wv >> 1;
  int lr = lane & 15, q = lane >> 4;
  int rdc = (q ^ ((lane >> 1) & 3)) * 8;
  int srow = lane >> 2;
  int gch = ((lane & 3) ^ ((lane >> 3) & 3)) * 8;

  int ra = wv * 32 + srow;
  int tokA0 = tok_of_row[grow0 + min(ra, nrows - 1)];
  int tokA1 = tok_of_row[grow0 + min(ra + 16, nrows - 1)];
  const bf16_t* gA0 = xbf + (size_t)tokA0 * HD + gch;
  const bf16_t* gA1 = xbf + (size_t)tokA1 * HD + gch;
  const bf16_t* p1 = w1b + (size_t)((e * NB1 + nb) * KC1) * 2048 + tid * 8;
  const bf16_t* p3 = w3b + (size_t)((e * NB1 + nb) * KC1) * 2048 + tid * 8;
  bf16_t* lA0 = &Abuf[(wv * 32) * 32];
  bf16_t* lA1 = &Abuf[(wv * 32 + 16) * 32];
  bf16_t* lB1 = &B1buf[wv * 512];
  bf16_t* lB3 = &B3buf[wv * 512];

  floatx4 accg[4][2] = {};
  floatx4 accu[4][2] = {};

  for (int kk = 0; kk < KC1; ++kk) {
    __syncthreads();
    gld16(gA0, lA0); gld16(gA1, lA1);
    gld16(p1, lB1); gld16(p3, lB3);
    gA0 += 32; gA1 += 32; p1 += 2048; p3 += 2048;
    __syncthreads();
    bf16x8 af[4], b1f[2], b3f[2];
#pragma unroll
    for (int i = 0; i < 4; ++i) af[i] = *(const bf16x8*)&Abuf[(wm * 64 + i * 16 + lr) * 32 + rdc];
#pragma unroll
    for (int i = 0; i < 2; ++i) b1f[i] = *(const bf16x8*)&B1buf[(wn * 32 + i * 16 + lr) * 32 + rdc];
#pragma unroll
    for (int i = 0; i < 2; ++i) b3f[i] = *(const bf16x8*)&B3buf[(wn * 32 + i * 16 + lr) * 32 + rdc];
#pragma unroll
    for (int i = 0; i < 4; ++i)
#pragma unroll
      for (int jj = 0; jj < 2; ++jj) {
        accg[i][jj] = __builtin_amdgcn_mfma_f32_16x16x32_bf16(af[i], b1f[jj], accg[i][jj], 0, 0, 0);
        accu[i][jj] = __builtin_amdgcn_mfma_f32_16x16x32_bf16(af[i], b3f[jj], accu[i][jj], 0, 0, 0);
      }
  }
#pragma unroll
  for (int i = 0; i < 4; ++i)
#pragma unroll
    for (int r = 0; r < 4; ++r) {
      int rl = wm * 64 + i * 16 + q * 4 + r;
      if (rl < nrows) {
        size_t rb = (size_t)(grow0 + rl) * ID + nb * 64 + wn * 32 + lr;
#pragma unroll
        for (int jj = 0; jj < 2; ++jj) {
          float gg = accg[i][jj][r], uu = accu[i][jj][r];
          float sg = gg / (1.f + __expf(-gg));
          h_ws[rb + jj * 16] = (bf16_t)(sg * uu);
        }
      }
    }
}

// ---------------- K4: grouped GEMM2 + fused combine (atomicAdd) ----------------
// grid 1152: bx = e + 8*(nb*RT + rt); tile 128m x 64n
__global__ __launch_bounds__(256, 4)
void k_gemm2(const bf16_t* __restrict__ h_ws, const bf16_t* __restrict__ w2b,
             const int* __restrict__ tok_of_row, const float* __restrict__ wgt_of_row,
             const int2* __restrict__ cnt_start, float* __restrict__ out) {
  int e = blockIdx.x & 7;
  int t = blockIdx.x >> 3;
  int nb = t / RT, rt = t - nb * RT;
  int2 cs = cnt_start[e];
  int nrows = cs.y - rt * 128;
  if (nrows <= 0) return;
  if (nrows > 128) nrows = 128;
  int grow0 = cs.x + rt * 128;

  __shared__ __attribute__((aligned(16))) bf16_t Abuf[128 * 32];
  __shared__ __attribute__((aligned(16))) bf16_t Bbuf[64 * 32];

  int tid = threadIdx.x;
  int lane = tid & 63, wv = tid >> 6;
  int wm = wv & 1, wn = wv >> 1;
  int lr = lane & 15, q = lane >> 4;
  int rdc = (q ^ ((lane >> 1) & 3)) * 8;
  int srow = lane >> 2;
  int gch = ((lane & 3) ^ ((lane >> 3) & 3)) * 8;

  int ra = wv * 32 + srow;
  const bf16_t* gA0 = h_ws + (size_t)(grow0 + min(ra, nrows - 1)) * ID + gch;
  const bf16_t* gA1 = h_ws + (size_t)(grow0 + min(ra + 16, nrows - 1)) * ID + gch;
  const bf16_t* pB = w2b + (size_t)((e * NB2 + nb) * KC2) * 2048 + tid * 8;
  bf16_t* lA0 = &Abuf[(wv * 32) * 32];
  bf16_t* lA1 = &Abuf[(wv * 32 + 16) * 32];
  bf16_t* lB = &Bbuf[wv * 512];

  floatx4 acc[4][2] = {};

  for (int kk = 0; kk < KC2; ++kk) {
    __syncthreads();
    gld16(gA0, lA0); gld16(gA1, lA1);
    gld16(pB, lB);
    gA0 += 32; gA1 += 32; pB += 2048;
    __syncthreads();
    bf16x8 af[4], bfr[2];
#pragma unroll
    for (int i = 0; i < 4; ++i) af[i] = *(const bf16x8*)&Abuf[(wm * 64 + i * 16 + lr) * 32 + rdc];
#pragma unroll
    for (int i = 0; i < 2; ++i) bfr[i] = *(const bf16x8*)&Bbuf[(wn * 32 + i * 16 + lr) * 32 + rdc];
#pragma unroll
    for (int i = 0; i < 4; ++i)
#pragma unroll
      for (int jj = 0; jj < 2; ++jj)
        acc[i][jj] = __builtin_amdgcn_mfma_f32_16x16x32_bf16(af[i], bfr[jj], acc[i][jj], 0, 0, 0);
  }
#pragma unroll
  for (int i = 0; i < 4; ++i)
#pragma unroll
    for (int r = 0; r < 4; ++r) {
      int rl = wm * 64 + i * 16 + q * 4 + r;
      if (rl < nrows) {
        int grow = grow0 + rl;
        int tok = tok_of_row[grow];
        float wgt = wgt_of_row[grow];
        size_t ob = (size_t)tok * HD + nb * 64 + wn * 32 + lr;
#pragma unroll
        for (int jj = 0; jj < 2; ++jj)
          atomicAdd(&out[ob + jj * 16], wgt * acc[i][jj][r]);
      }
    }
}

extern "C" void kernel_launch(void* const* d_in, const int* in_sizes, int n_in,
                              void* d_out, int out_size, void* d_ws, size_t ws_size,
                              hipStream_t stream) {
  const float* x  = (const float*)d_in[0];
  const float* wg = (const float*)d_in[1];
  const float* w1 = (const float*)d_in[2];
  const float* w3 = (const float*)d_in[3];
  const float* w2 = (const float*)d_in[4];
  float* out = (float*)d_out;

  char* ws = (char*)d_ws;
  bf16_t* xbf  = (bf16_t*)(ws + 0);          //  3,145,728
  bf16_t* w1b  = (bf16_t*)(ws + 3145728);    // 18,874,368
  bf16_t* w3b  = (bf16_t*)(ws + 22020096);   // 18,874,368
  bf16_t* w2b  = (bf16_t*)(ws + 40894464);   // 18,874,368
  bf16_t* h_ws = (bf16_t*)(ws + 59768832);   // 12,582,912
  float*  probs8     = (float*)(ws + 72351744);   // 65,536
  int2*   idx2       = (int2*)(ws + 72417280);
  float2* wc2        = (float2*)(ws + 72433664);
  int*    tok_of_row = (int*)(ws + 72450048);
  float*  wgt_of_row = (float*)(ws + 72466432);
  int2*   cnt_start  = (int2*)(ws + 72482816);

  float* aux_out = out + (size_t)T_TOK * HD;

  k_prep<<<2240, 256, 0, stream>>>(x, wg, w1, w3, w2, xbf, w1b, w3b, w2b,
                                   idx2, wc2, probs8, out);
  k_scan<<<1, 1024, 0, stream>>>(idx2, wc2, probs8, tok_of_row, wgt_of_row,
                                 cnt_start, aux_out);
  k_gemm1<<<8 * NB1 * RT, 256, 0, stream>>>(xbf, w1b, w3b, tok_of_row,
                                            cnt_start, h_ws);
  k_gemm2<<<8 * NB2 * RT, 256, 0, stream>>>(h_ws, w2b, tok_of_row, wgt_of_row,
                                            cnt_start, out);
}